// Round 14
// baseline (6889.178 us; speedup 1.0000x reference)
//
#include <hip/hip_runtime.h>
#include <math.h>

#define N 2048
#define PSTRIDE 24
#define CCAP (1u << 20)
#define ECAP (1u << 19)
#define ELCAP 12288u  // edges cached in LDS (96KB)

typedef unsigned int uint;
typedef unsigned short ushort;
typedef unsigned long long ull;

// ws layout (bytes):
#define CTR_OFF   0        // ccnt@0, ecnt@64, mcount@128
#define PREP_OFF  256      // 2048*24 f32
#define CAND_OFF  196864   // u32[CCAP]
#define ETMP_OFF  4391168  // u64[ECAP]
#define ECSR_OFF  8585472  // u64[ECAP]
#define RINF_OFF  12779776 // u32[2048]
#define MARK_OFF  12796160 // u32[2048]
#define GCM_OFF   12804352 // u32[2048]
#define MLIST_OFF 12812544 // ushort[2048]
#define KOUT_OFF  12816640 // u64[2048]
#define NEED      12833024ull

// ---------- DPP wave-64 max reduction (proven r10-r13) ----------
__device__ __forceinline__ uint wave_umax_bcast(uint v) {
  int x = (int)v;
  int t;
  t = __builtin_amdgcn_update_dpp(0, x, 0x111, 0xF, 0xF, false); x = (int)((uint)x > (uint)t ? (uint)x : (uint)t);
  t = __builtin_amdgcn_update_dpp(0, x, 0x112, 0xF, 0xF, false); x = (int)((uint)x > (uint)t ? (uint)x : (uint)t);
  t = __builtin_amdgcn_update_dpp(0, x, 0x114, 0xF, 0xF, false); x = (int)((uint)x > (uint)t ? (uint)x : (uint)t);
  t = __builtin_amdgcn_update_dpp(0, x, 0x118, 0xF, 0xF, false); x = (int)((uint)x > (uint)t ? (uint)x : (uint)t);
  t = __builtin_amdgcn_update_dpp(0, x, 0x142, 0xF, 0xF, false); x = (int)((uint)x > (uint)t ? (uint)x : (uint)t);
  t = __builtin_amdgcn_update_dpp(0, x, 0x143, 0xF, 0xF, false); x = (int)((uint)x > (uint)t ? (uint)x : (uint)t);
  return (uint)__builtin_amdgcn_readlane(x, 63);
}

// Per-box precompute + zero counters/rowcnt/mark.
__global__ __launch_bounds__(256) void prep_kernel(const float* __restrict__ boxes,
                                                   float* __restrict__ prep,
                                                   uint* __restrict__ ctrs,
                                                   uint* __restrict__ rowcnt,
                                                   uint* __restrict__ mark) {
#pragma clang fp contract(off)
  int i = blockIdx.x * 256 + threadIdx.x;
  if (blockIdx.x == 0 && threadIdx.x < 3) ctrs[threadIdx.x * 16] = 0u;
  if (i >= N) return;
  rowcnt[i] = 0u;
  mark[i] = 0u;
  float xc = boxes[i * 5 + 0], yc = boxes[i * 5 + 1];
  float w = boxes[i * 5 + 2], h = boxes[i * 5 + 3], th = boxes[i * 5 + 4];
  float t = th * 0.017453292519943295f;
  float c = (float)cos((double)t);
  float s = (float)sin((double)t);
  float w2 = w * 0.5f, h2 = h * 0.5f;
  float lx[4] = {-w2, w2, w2, -w2};
  float ly[4] = {-h2, -h2, h2, h2};
  float* P = prep + i * PSTRIDE;
#pragma unroll
  for (int k = 0; k < 4; k++) {
    P[k * 2 + 0] = (xc + lx[k] * c) - ly[k] * s;
    P[k * 2 + 1] = (yc + lx[k] * s) + ly[k] * c;
  }
  P[8] = xc; P[9] = yc; P[10] = c; P[11] = s; P[12] = w2; P[13] = h2;
  P[14] = w * h;
  P[15] = sqrtf(w2 * w2 + h2 * h2);
  P[16] = w2 * fabsf(c) + h2 * fabsf(s) + 1e-4f;
  P[17] = w2 * fabsf(s) + h2 * fabsf(c) + 1e-4f;
}

// AABB IoU-upper-bound filter (bit-exact prune, proven r12/r13) with
// block-aggregated compaction: ONE global atomic per block (was per-wave).
__global__ __launch_bounds__(256) void cand_kernel(const float* __restrict__ prep,
                                                   uint* __restrict__ cand,
                                                   uint* __restrict__ ccnt) {
  __shared__ uint wsum[4];
  int tid = threadIdx.x;
  int widx = tid >> 6, lane = tid & 63;
  uint pk[4]; bool kp[4]; uint off[4];
  uint accum = 0;
#pragma unroll
  for (int it = 0; it < 4; it++) {
    uint gid = blockIdx.x * 1024u + (uint)it * 256u + (uint)tid;
    uint i = gid >> 11, j = gid & 2047u;
    const float* Pi = prep + i * PSTRIDE;
    const float* Pj = prep + j * PSTRIDE;
    float ox = (Pi[16] + Pj[16]) - fabsf(Pi[8] - Pj[8]);
    float oy = (Pi[17] + Pj[17]) - fabsf(Pi[9] - Pj[9]);
    bool keep = (i != j) && (ox > 0.0f) && (oy > 0.0f);
    if (keep) {
      float aa = Pi[14] + Pj[14];
      float iub = fminf(ox * oy, fminf(Pi[14], Pj[14]));
      keep = (13.0f * iub > 2.99f * aa);
    }
    ull m = __ballot(keep);
    off[it] = accum + (uint)__popcll(m & ((1ull << lane) - 1ull));
    accum += (uint)__popcll(m);
    kp[it] = keep;
    pk[it] = (i << 11) | j;
  }
  if (lane == 0) wsum[widx] = accum;
  __syncthreads();
  if (tid == 0) {
    uint t0 = wsum[0], t1 = wsum[1], t2 = wsum[2], t3 = wsum[3];
    uint b = atomicAdd(ccnt, t0 + t1 + t2 + t3);
    wsum[0] = b; wsum[1] = b + t0; wsum[2] = b + t0 + t1; wsum[3] = b + t0 + t1 + t2;
  }
  __syncthreads();
  uint wb = wsum[widx];
#pragma unroll
  for (int it = 0; it < 4; it++) {
    if (kp[it]) {
      uint pos = wb + off[it];
      if (pos < CCAP) cand[pos] = pk[it];
    }
  }
}

// Rotated-rect intersection weight — bit-exact fp32 mirror (proven r8-r13).
__device__ float pair_weight(const float* __restrict__ Pi, const float* __restrict__ Pj) {
#pragma clang fp contract(off)
  float ax[4], ay[4], bx[4], by[4];
#pragma unroll
  for (int k = 0; k < 4; k++) {
    ax[k] = Pi[2 * k]; ay[k] = Pi[2 * k + 1];
    bx[k] = Pj[2 * k]; by[k] = Pj[2 * k + 1];
  }
  float ptsx[24], ptsy[24];
  bool msk[24];
#pragma unroll
  for (int e = 0; e < 4; e++) {
    float Ax = ax[e], Ay = ay[e];
    float BAx = ax[(e + 1) & 3] - Ax, BAy = ay[(e + 1) & 3] - Ay;
#pragma unroll
    for (int f = 0; f < 4; f++) {
      float Cx = bx[f], Cy = by[f];
      float DCx = bx[(f + 1) & 3] - Cx, DCy = by[(f + 1) & 3] - Cy;
      float CAx = Cx - Ax, CAy = Cy - Ay;
      float den = BAx * DCy - BAy * DCx;
      bool dok = fabsf(den) > 1e-12f;
      float dens = dok ? den : 1.0f;
      float t = (CAx * DCy - CAy * DCx) / dens;
      float u = (CAx * BAy - CAy * BAx) / dens;
      int id = e * 4 + f;
      ptsx[id] = Ax + t * BAx;
      ptsy[id] = Ay + t * BAy;
      msk[id] = dok && (t >= 0.0f) && (t <= 1.0f) && (u >= 0.0f) && (u <= 1.0f);
    }
  }
  float xcj = Pj[8], ycj = Pj[9], cj = Pj[10], sj = Pj[11], w2j = Pj[12], h2j = Pj[13];
  float xci = Pi[8], yci = Pi[9], ci = Pi[10], si = Pi[11], w2i = Pi[12], h2i = Pi[13];
#pragma unroll
  for (int k = 0; k < 4; k++) {
    float dx = ax[k] - xcj, dy = ay[k] - ycj;
    float xl = dx * cj + dy * sj;
    float yl = -dx * sj + dy * cj;
    ptsx[16 + k] = ax[k]; ptsy[16 + k] = ay[k];
    msk[16 + k] = (fabsf(xl) <= w2j + 1e-5f) && (fabsf(yl) <= h2j + 1e-5f);
  }
#pragma unroll
  for (int k = 0; k < 4; k++) {
    float dx = bx[k] - xci, dy = by[k] - yci;
    float xl = dx * ci + dy * si;
    float yl = -dx * si + dy * ci;
    ptsx[20 + k] = bx[k]; ptsy[20 + k] = by[k];
    msk[20 + k] = (fabsf(xl) <= w2i + 1e-5f) && (fabsf(yl) <= h2i + 1e-5f);
  }
  int cnt = 0;
  float sx = 0.f, sy = 0.f;
#pragma unroll
  for (int k = 0; k < 24; k++) {
    if (msk[k]) { cnt++; sx += ptsx[k]; sy += ptsy[k]; }
  }
  float fc = (float)(cnt > 1 ? cnt : 1);
  float ctx = sx / fc, cty = sy / fc;
  float ang[32], px[32], py[32];
  int idp[32];
#pragma unroll
  for (int k = 0; k < 24; k++) {
    float rx = ptsx[k] - ctx, ry = ptsy[k] - cty;
    px[k] = rx; py[k] = ry; idp[k] = k;
    ang[k] = msk[k] ? (float)atan2((double)ry, (double)rx) : 1.0e3f;
  }
#pragma unroll
  for (int k = 24; k < 32; k++) { ang[k] = 1.0e30f; px[k] = 0.f; py[k] = 0.f; idp[k] = k; }
#pragma unroll
  for (int k = 2; k <= 32; k <<= 1) {
#pragma unroll
    for (int j = k >> 1; j > 0; j >>= 1) {
#pragma unroll
      for (int x = 0; x < 32; x++) {
        int l = x ^ j;
        if (l > x) {
          bool up = ((x & k) == 0);
          bool gt = (ang[x] > ang[l]) || (ang[x] == ang[l] && idp[x] > idp[l]);
          if (gt == up) {
            float t0 = ang[x]; ang[x] = ang[l]; ang[l] = t0;
            float t1 = px[x]; px[x] = px[l]; px[l] = t1;
            float t2 = py[x]; py[x] = py[l]; py[l] = t2;
            int t3 = idp[x]; idp[x] = idp[l]; idp[l] = t3;
          }
        }
      }
    }
  }
  float term[24];
#pragma unroll
  for (int x = 0; x < 24; x++) {
    int nx = (x + 1 < cnt) ? x + 1 : 0;
    float cr = px[x] * py[nx] - py[x] * px[nx];
    term[x] = (x < cnt) ? cr : 0.0f;
  }
  float r[8];
#pragma unroll
  for (int j = 0; j < 8; j++) r[j] = (term[j] + term[j + 8]) + term[j + 16];
  float ssum = ((r[0] + r[1]) + (r[2] + r[3])) + ((r[4] + r[5]) + (r[6] + r[7]));
  float area = 0.5f * fabsf(ssum);
  float inter = (cnt >= 3) ? area : 0.0f;
  float iou = inter / ((Pi[14] + Pj[14] - inter) + 1e-9f);
  return (iou > 0.3f) ? (1.0f - iou) : 1.0f;
}

// Heavy geometry on candidates (grid-stride); emit sparse edge iff w != 1.
__global__ __launch_bounds__(64, 2) void weight_kernel(const float* __restrict__ prep,
                                                       const uint* __restrict__ cand,
                                                       const uint* __restrict__ ccnt,
                                                       ull* __restrict__ etmp,
                                                       uint* __restrict__ ecnt,
                                                       uint* __restrict__ rowcnt,
                                                       uint* __restrict__ mark) {
  uint n = *ccnt;
  if (n > CCAP) n = CCAP;
  for (uint idx = blockIdx.x * 64u + threadIdx.x; idx < n; idx += gridDim.x * 64u) {
    uint pk = cand[idx];
    uint i = pk >> 11, j = pk & 2047u;
    float w = pair_weight(prep + i * PSTRIDE, prep + j * PSTRIDE);
    if (w != 1.0f) {
      uint pos = atomicAdd(ecnt, 1u);
      if (pos < ECAP) {
        etmp[pos] = (((ull)__float_as_uint(w)) << 32) | (ull)pk;
        atomicAdd(rowcnt + i, 1u);
        mark[i] = 1u;
        mark[j] = 1u;
      }
    }
  }
}

// CSR finalize + edge scatter fused (one workgroup, LDS cursors).
__global__ __launch_bounds__(1024) void csr_fin(uint* __restrict__ rinfo,
                                                const uint* __restrict__ mark,
                                                ushort* __restrict__ mlist,
                                                uint* __restrict__ gcm,
                                                uint* __restrict__ mcount,
                                                const ull* __restrict__ etmp,
                                                const uint* __restrict__ ecnt,
                                                ull* __restrict__ ecsr) {
  __shared__ uint pre[N];
  __shared__ uint curL[N];
  __shared__ uint msh;
  int tid = threadIdx.x;
  uint c0 = rinfo[tid], c1 = rinfo[tid + 1024];
  pre[tid] = c0; pre[tid + 1024] = c1;
  if (tid == 0) msh = 0;
  __syncthreads();
  for (int d = 1; d < N; d <<= 1) {
    uint a0 = pre[tid] + ((tid >= d) ? pre[tid - d] : 0);
    uint a1 = pre[tid + 1024] + ((tid + 1024 >= d) ? pre[tid + 1024 - d] : 0);
    __syncthreads();
    pre[tid] = a0; pre[tid + 1024] = a1;
    __syncthreads();
  }
  uint p0 = pre[tid] - c0, p1 = pre[tid + 1024] - c1;
  rinfo[tid] = p0 | (c0 << 20);
  rinfo[tid + 1024] = p1 | (c1 << 20);
  curL[tid] = p0;
  curL[tid + 1024] = p1;
  if (mark[tid]) { uint m = atomicAdd(&msh, 1u); mlist[m] = (ushort)tid; gcm[tid] = m; }
  if (mark[tid + 1024]) { uint m = atomicAdd(&msh, 1u); mlist[m] = (ushort)(tid + 1024); gcm[tid + 1024] = m; }
  __syncthreads();
  if (tid == 0) *mcount = msh;
  uint E = *ecnt;
  if (E > ECAP) E = ECAP;
  for (uint e = (uint)tid; e < E; e += 1024u) {
    ull ed = etmp[e];
    uint lo = (uint)ed;
    uint i = (lo >> 11) & 2047u, j = lo & 2047u;
    uint pos = atomicAdd(&curL[i], 1u);
    ecsr[pos] = (ed & 0xFFFFFFFF00000000ull) | (ull)gcm[j];
  }
}

// Sequential soft-NMS over members, ONE wave. Per-lane register TOP-4 with
// static lower bound Bs (= 4th-best key at rebuild): untracked slots only
// decay, so untracked <= Bs forever. Decayed tracked entry kept in place iff
// new key >= Bs (then re-sorted), else dropped. Pop shifts. Rebuild only when
// the list empties (~every 4th pop of a lane).
__global__ __launch_bounds__(64) void scan_sub(const float* __restrict__ scores,
                                               const ushort* __restrict__ mlist,
                                               const uint* __restrict__ mcount,
                                               const uint* __restrict__ rinfo_g,
                                               const ull* __restrict__ ecsr,
                                               const uint* __restrict__ ecnt,
                                               const uint* __restrict__ mark,
                                               ull* __restrict__ kout) {
#pragma clang fp contract(off)
  __shared__ ull mkey[N];
  __shared__ uint rinfo[N];
  __shared__ ull eld[ELCAP];
  const int lane = threadIdx.x;
#pragma unroll
  for (int k = 0; k < 8; k++) {
    int i4 = lane + 64 * k;
    ((uint4*)rinfo)[i4] = ((const uint4*)rinfo_g)[i4];
  }
#pragma unroll
  for (int k = 0; k < 32; k++) mkey[lane + 64 * k] = 0ull;
#pragma unroll
  for (int k = 0; k < 32; k++) {
    int col = lane + 64 * k;
    if (!mark[col]) {
      uint b = __float_as_uint(scores[col]);
      kout[col] = (((ull)b) << 32) | (ull)(uint)(2048 - col);
    }
  }
  uint E = *ecnt;
  if (E > ECAP) E = ECAP;
  bool use_lds = (E <= ELCAP);
  if (use_lds) {
    uint n4 = (E + 1) >> 1;
    for (uint q = (uint)lane; q < n4; q += 64u)
      ((uint4*)eld)[q] = ((const uint4*)ecsr)[q];
  }
  int M = (int)*mcount;
  int nsl = (M + 63) >> 6;
  for (int g = 0; g < nsl; g++) {
    int m = lane + 64 * g;
    if (m < M) {
      int col = (int)mlist[m];
      uint b = __float_as_uint(scores[col]);
      mkey[m] = (((ull)b) << 32) | (ull)(uint)(2048 - col);
    }
  }
  asm volatile("s_waitcnt lgkmcnt(0) vmcnt(0)" ::: "memory");
  ull k0 = 0, k1 = 0, k2 = 0, k3 = 0, Bs = 0;
  int m0 = -1, m1 = -1, m2 = -1, m3 = -1;
  bool done = false;
  auto rebuild = [&]() {
    k0 = k1 = k2 = k3 = 0;
    m0 = m1 = m2 = m3 = -1;
    for (int g = 0; g < nsl; g++) {
      int m = lane + 64 * g;
      if (m < M) {
        ull k = mkey[m];
        if (k > k0)      { k3 = k2; m3 = m2; k2 = k1; m2 = m1; k1 = k0; m1 = m0; k0 = k; m0 = m; }
        else if (k > k1) { k3 = k2; m3 = m2; k2 = k1; m2 = m1; k1 = k; m1 = m; }
        else if (k > k2) { k3 = k2; m3 = m2; k2 = k; m2 = m; }
        else if (k > k3) { k3 = k; m3 = m; }
      }
    }
    Bs = k3;           // untracked <= Bs (0 if <4 live keys => never drop)
    done = (k0 == 0);  // all consumed
  };
  rebuild();
  for (int t = 0; t < M; ++t) {
    uint hi = (uint)(k0 >> 32);
    uint ghi = wave_umax_bcast(hi);
    if (!((double)__uint_as_float(ghi) > 0.001)) break;
    uint lo = (uint)k0;
    uint cnd = (hi == ghi) ? lo : 0u;
    uint glo = wave_umax_bcast(cnd);
    int bj = 2048 - (int)glo;
    if (hi == ghi && lo == glo && k0 != 0ull) {  // unique owner pops
      mkey[m0] = 0ull;
      kout[bj] = (((ull)ghi) << 32) | (ull)glo;
      k0 = k1; m0 = m1; k1 = k2; m1 = m2; k2 = k3; m2 = m3; k3 = 0; m3 = -1;
    }
    uint info = rinfo[bj];
    uint ptr = info & 0xFFFFFu;
    uint deg = info >> 20;
    if (use_lds) {
      for (uint e = (uint)lane; e < deg; e += 64u) {
        ull ed = eld[ptr + e];
        uint mt = (uint)ed & 2047u;
        float w = __uint_as_float((uint)(ed >> 32));
        ull ok = mkey[mt];
        float nv = __uint_as_float((uint)(ok >> 32)) * w;
        mkey[mt] = (((ull)__float_as_uint(nv)) << 32) | (ok & 0xFFFFFFFFull);
      }
    } else {
      for (uint e = (uint)lane; e < deg; e += 64u) {
        ull ed = ecsr[ptr + e];
        uint mt = (uint)ed & 2047u;
        float w = __uint_as_float((uint)(ed >> 32));
        ull ok = mkey[mt];
        float nv = __uint_as_float((uint)(ok >> 32)) * w;
        mkey[mt] = (((ull)__float_as_uint(nv)) << 32) | (ok & 0xFFFFFFFFull);
      }
    }
    asm volatile("s_waitcnt lgkmcnt(0)" ::: "memory");
    // validate tracked entries (4 independent LDS reads)
    ull a0 = mkey[m0 >= 0 ? m0 : 0];
    ull a1 = mkey[m1 >= 0 ? m1 : 0];
    ull a2 = mkey[m2 >= 0 ? m2 : 0];
    ull a3 = mkey[m3 >= 0 ? m3 : 0];
    bool c0 = (m0 >= 0) && (a0 != k0);
    bool c1 = (m1 >= 0) && (a1 != k1);
    bool c2 = (m2 >= 0) && (a2 != k2);
    bool c3 = (m3 >= 0) && (a3 != k3);
    if (c0 | c1 | c2 | c3) {  // rare: decay touched a tracked slot
      if (c0) { if (a0 >= Bs) k0 = a0; else { k0 = 0; m0 = -1; } }
      if (c1) { if (a1 >= Bs) k1 = a1; else { k1 = 0; m1 = -1; } }
      if (c2) { if (a2 >= Bs) k2 = a2; else { k2 = 0; m2 = -1; } }
      if (c3) { if (a3 >= Bs) k3 = a3; else { k3 = 0; m3 = -1; } }
      ull tk; int tm;
#define CE(x, y, mx, my) if (x < y) { tk = x; x = y; y = tk; tm = mx; mx = my; my = tm; }
      CE(k0, k1, m0, m1) CE(k2, k3, m2, m3) CE(k0, k2, m0, m2) CE(k1, k3, m1, m3) CE(k1, k2, m1, m2)
#undef CE
    }
    if (k0 == 0ull && !done) rebuild();
  }
  asm volatile("s_waitcnt lgkmcnt(0)" ::: "memory");
  for (int g = 0; g < nsl; g++) {
    int m = lane + 64 * g;
    if (m < M) {
      ull key = mkey[m];
      if (key != 0ull) {
        int col = 2048 - (int)(uint)key;
        kout[col] = key;
      }
    }
  }
}

// Sort 2048 keys descending and emit (order, keep, rec). Proven r11-r13.
__global__ __launch_bounds__(1024) void sort_out(const ull* __restrict__ kout,
                                                 float* __restrict__ out) {
  __shared__ ull keys[N];
  int tid = threadIdx.x;
  keys[tid] = kout[tid];
  keys[tid + 1024] = kout[tid + 1024];
  __syncthreads();
  for (int k = 2; k <= N; k <<= 1) {
    for (int jj = k >> 1; jj > 0; jj >>= 1) {
      int i1 = ((tid & ~(jj - 1)) << 1) | (tid & (jj - 1));
      int i2 = i1 | jj;
      ull a = keys[i1], b = keys[i2];
      bool up = ((i1 & k) == 0);
      if (up ? (a < b) : (a > b)) { keys[i1] = b; keys[i2] = a; }
      __syncthreads();
    }
  }
#pragma unroll
  for (int h = 0; h < 2; h++) {
    int r = tid + 1024 * h;
    ull key = keys[r];
    int col = 2048 - (int)(uint)key;
    float v = __uint_as_float((uint)(key >> 32));
    out[r] = (float)col;
    out[N + r] = ((double)v > 0.001) ? 1.0f : 0.0f;
    out[2 * N + r] = v;
  }
}

// Tiny-ws fallback: on-the-fly dense scan (proven round 8 structure).
__global__ __launch_bounds__(1024) void scan_fly(const float* __restrict__ prep,
                                                 const float* __restrict__ scores,
                                                 float* __restrict__ out) {
  __shared__ float sc[N];
  __shared__ unsigned char sel[N];
  __shared__ float rv[16];
  __shared__ int ri[16];
  int tid = threadIdx.x;
  sc[tid] = scores[tid];
  sc[tid + 1024] = scores[tid + 1024];
  sel[tid] = 0;
  sel[tid + 1024] = 0;
  __syncthreads();
  const float NINF = -__builtin_inff();
  for (int t = 0; t < N; ++t) {
    float v0 = sel[tid] ? NINF : sc[tid];
    float v1 = sel[tid + 1024] ? NINF : sc[tid + 1024];
    float bv; int bi;
    if (v0 >= v1) { bv = v0; bi = tid; } else { bv = v1; bi = tid + 1024; }
#pragma unroll
    for (int off = 32; off > 0; off >>= 1) {
      float ov = __shfl_down(bv, off);
      int oi = __shfl_down(bi, off);
      if (ov > bv || (ov == bv && oi < bi)) { bv = ov; bi = oi; }
    }
    if ((tid & 63) == 0) { rv[tid >> 6] = bv; ri[tid >> 6] = bi; }
    __syncthreads();
    float mv = rv[0]; int mi = ri[0];
#pragma unroll
    for (int k = 1; k < 16; k++) {
      float ov = rv[k]; int oi = ri[k];
      if (ov > mv || (ov == mv && oi < mi)) { mv = ov; mi = oi; }
    }
    if (tid == 0) {
      out[t] = (float)mi;
      out[N + t] = (mv > 0.001f) ? 1.0f : 0.0f;
      out[2 * N + t] = mv;
    }
    if (tid == (mi & 1023)) sel[mi] = 1;
    if (mv > 0.001f) {
      const float* Pm = prep + mi * PSTRIDE;
#pragma unroll
      for (int half = 0; half < 2; half++) {
        int j = tid + half * 1024;
        if (!sel[j]) {
          const float* Pj = prep + j * PSTRIDE;
          float dx = Pm[8] - Pj[8], dy = Pm[9] - Pj[9];
          float rr = Pm[15] + Pj[15] + 1.0f;
          float w = 1.0f;
          if (dx * dx + dy * dy <= rr * rr) w = pair_weight(Pm, Pj);
          sc[j] *= w;
        }
      }
    }
    __syncthreads();
  }
}

extern "C" void kernel_launch(void* const* d_in, const int* in_sizes, int n_in,
                              void* d_out, int out_size, void* d_ws, size_t ws_size,
                              hipStream_t stream) {
  const float* boxes = (const float*)d_in[0];
  const float* scores = (const float*)d_in[1];
  if (n_in >= 2 && in_sizes[0] == N && in_sizes[1] == 5 * N) {
    boxes = (const float*)d_in[1];
    scores = (const float*)d_in[0];
  }
  float* out = (float*)d_out;
  char* ws = (char*)d_ws;
  uint* ccnt = (uint*)(ws + CTR_OFF);
  uint* ecnt = (uint*)(ws + CTR_OFF + 64);
  uint* mcount = (uint*)(ws + CTR_OFF + 128);
  float* prep = (float*)(ws + PREP_OFF);

  if (ws_size >= NEED) {
    uint* cand = (uint*)(ws + CAND_OFF);
    ull* etmp = (ull*)(ws + ETMP_OFF);
    ull* ecsr = (ull*)(ws + ECSR_OFF);
    uint* rinfo = (uint*)(ws + RINF_OFF);
    uint* mark = (uint*)(ws + MARK_OFF);
    uint* gcm = (uint*)(ws + GCM_OFF);
    ushort* mlist = (ushort*)(ws + MLIST_OFF);
    ull* kout = (ull*)(ws + KOUT_OFF);
    prep_kernel<<<8, 256, 0, stream>>>(boxes, prep, (uint*)ws, rinfo, mark);
    cand_kernel<<<4096, 256, 0, stream>>>(prep, cand, ccnt);
    weight_kernel<<<1024, 64, 0, stream>>>(prep, cand, ccnt, etmp, ecnt, rinfo, mark);
    csr_fin<<<1, 1024, 0, stream>>>(rinfo, mark, mlist, gcm, mcount, etmp, ecnt, ecsr);
    scan_sub<<<1, 64, 0, stream>>>(scores, mlist, mcount, rinfo, ecsr, ecnt, mark, kout);
    sort_out<<<1, 1024, 0, stream>>>(kout, out);
  } else {
    prep_kernel<<<8, 256, 0, stream>>>(boxes, prep, (uint*)ws,
                                       (uint*)(ws + 256 + 196608),
                                       (uint*)(ws + 256 + 196608 + 8192));
    scan_fly<<<1, 1024, 0, stream>>>(prep, scores, out);
  }
}

// Round 15
// 2202.156 us; speedup vs baseline: 3.1284x; 3.1284x over previous
//
#include <hip/hip_runtime.h>
#include <math.h>

#define N 2048
#define PSTRIDE 24
#define CCAP (1u << 20)
#define ECAP (1u << 19)
#define ELCAP 12288u  // edges cached in LDS (96KB)

typedef unsigned int uint;
typedef unsigned short ushort;
typedef unsigned long long ull;

// ws layout (bytes):
#define CTR_OFF   0        // ccnt@0, ecnt@64, mcount@128
#define PREP_OFF  256      // 2048*24 f32
#define CAND_OFF  196864   // u32[CCAP]
#define ETMP_OFF  4391168  // u64[ECAP]
#define ECSR_OFF  8585472  // u64[ECAP]
#define RINF_OFF  12779776 // u32[2048]
#define MARK_OFF  12796160 // u32[2048]
#define GCM_OFF   12804352 // u32[2048]
#define MLIST_OFF 12812544 // ushort[2048]
#define KOUT_OFF  12816640 // u64[2048]
#define NEED      12833024ull

// ---------- DPP wave-64 max reduction (proven r10-r14) ----------
__device__ __forceinline__ uint wave_umax_bcast(uint v) {
  int x = (int)v;
  int t;
  t = __builtin_amdgcn_update_dpp(0, x, 0x111, 0xF, 0xF, false); x = (int)((uint)x > (uint)t ? (uint)x : (uint)t);
  t = __builtin_amdgcn_update_dpp(0, x, 0x112, 0xF, 0xF, false); x = (int)((uint)x > (uint)t ? (uint)x : (uint)t);
  t = __builtin_amdgcn_update_dpp(0, x, 0x114, 0xF, 0xF, false); x = (int)((uint)x > (uint)t ? (uint)x : (uint)t);
  t = __builtin_amdgcn_update_dpp(0, x, 0x118, 0xF, 0xF, false); x = (int)((uint)x > (uint)t ? (uint)x : (uint)t);
  t = __builtin_amdgcn_update_dpp(0, x, 0x142, 0xF, 0xF, false); x = (int)((uint)x > (uint)t ? (uint)x : (uint)t);
  t = __builtin_amdgcn_update_dpp(0, x, 0x143, 0xF, 0xF, false); x = (int)((uint)x > (uint)t ? (uint)x : (uint)t);
  return (uint)__builtin_amdgcn_readlane(x, 63);
}

// Per-box precompute + zero counters/rowcnt/mark.
__global__ __launch_bounds__(256) void prep_kernel(const float* __restrict__ boxes,
                                                   float* __restrict__ prep,
                                                   uint* __restrict__ ctrs,
                                                   uint* __restrict__ rowcnt,
                                                   uint* __restrict__ mark) {
#pragma clang fp contract(off)
  int i = blockIdx.x * 256 + threadIdx.x;
  if (blockIdx.x == 0 && threadIdx.x < 3) ctrs[threadIdx.x * 16] = 0u;
  if (i >= N) return;
  rowcnt[i] = 0u;
  mark[i] = 0u;
  float xc = boxes[i * 5 + 0], yc = boxes[i * 5 + 1];
  float w = boxes[i * 5 + 2], h = boxes[i * 5 + 3], th = boxes[i * 5 + 4];
  float t = th * 0.017453292519943295f;
  float c = (float)cos((double)t);
  float s = (float)sin((double)t);
  float w2 = w * 0.5f, h2 = h * 0.5f;
  float lx[4] = {-w2, w2, w2, -w2};
  float ly[4] = {-h2, -h2, h2, h2};
  float* P = prep + i * PSTRIDE;
#pragma unroll
  for (int k = 0; k < 4; k++) {
    P[k * 2 + 0] = (xc + lx[k] * c) - ly[k] * s;
    P[k * 2 + 1] = (yc + lx[k] * s) + ly[k] * c;
  }
  P[8] = xc; P[9] = yc; P[10] = c; P[11] = s; P[12] = w2; P[13] = h2;
  P[14] = w * h;
  P[15] = sqrtf(w2 * w2 + h2 * h2);
  P[16] = w2 * fabsf(c) + h2 * fabsf(s) + 1e-4f;
  P[17] = w2 * fabsf(s) + h2 * fabsf(c) + 1e-4f;
}

// AABB IoU-upper-bound filter (bit-exact prune) + block-aggregated compaction.
__global__ __launch_bounds__(256) void cand_kernel(const float* __restrict__ prep,
                                                   uint* __restrict__ cand,
                                                   uint* __restrict__ ccnt) {
  __shared__ uint wsum[4];
  int tid = threadIdx.x;
  int widx = tid >> 6, lane = tid & 63;
  uint pk[4]; bool kp[4]; uint off[4];
  uint accum = 0;
#pragma unroll
  for (int it = 0; it < 4; it++) {
    uint gid = blockIdx.x * 1024u + (uint)it * 256u + (uint)tid;
    uint i = gid >> 11, j = gid & 2047u;
    const float* Pi = prep + i * PSTRIDE;
    const float* Pj = prep + j * PSTRIDE;
    float ox = (Pi[16] + Pj[16]) - fabsf(Pi[8] - Pj[8]);
    float oy = (Pi[17] + Pj[17]) - fabsf(Pi[9] - Pj[9]);
    bool keep = (i != j) && (ox > 0.0f) && (oy > 0.0f);
    if (keep) {
      float aa = Pi[14] + Pj[14];
      float iub = fminf(ox * oy, fminf(Pi[14], Pj[14]));
      keep = (13.0f * iub > 2.99f * aa);
    }
    ull m = __ballot(keep);
    off[it] = accum + (uint)__popcll(m & ((1ull << lane) - 1ull));
    accum += (uint)__popcll(m);
    kp[it] = keep;
    pk[it] = (i << 11) | j;
  }
  if (lane == 0) wsum[widx] = accum;
  __syncthreads();
  if (tid == 0) {
    uint t0 = wsum[0], t1 = wsum[1], t2 = wsum[2], t3 = wsum[3];
    uint b = atomicAdd(ccnt, t0 + t1 + t2 + t3);
    wsum[0] = b; wsum[1] = b + t0; wsum[2] = b + t0 + t1; wsum[3] = b + t0 + t1 + t2;
  }
  __syncthreads();
  uint wb = wsum[widx];
#pragma unroll
  for (int it = 0; it < 4; it++) {
    if (kp[it]) {
      uint pos = wb + off[it];
      if (pos < CCAP) cand[pos] = pk[it];
    }
  }
}

// Rotated-rect intersection weight — bit-exact fp32 mirror (proven r8-r14).
__device__ float pair_weight(const float* __restrict__ Pi, const float* __restrict__ Pj) {
#pragma clang fp contract(off)
  float ax[4], ay[4], bx[4], by[4];
#pragma unroll
  for (int k = 0; k < 4; k++) {
    ax[k] = Pi[2 * k]; ay[k] = Pi[2 * k + 1];
    bx[k] = Pj[2 * k]; by[k] = Pj[2 * k + 1];
  }
  float ptsx[24], ptsy[24];
  bool msk[24];
#pragma unroll
  for (int e = 0; e < 4; e++) {
    float Ax = ax[e], Ay = ay[e];
    float BAx = ax[(e + 1) & 3] - Ax, BAy = ay[(e + 1) & 3] - Ay;
#pragma unroll
    for (int f = 0; f < 4; f++) {
      float Cx = bx[f], Cy = by[f];
      float DCx = bx[(f + 1) & 3] - Cx, DCy = by[(f + 1) & 3] - Cy;
      float CAx = Cx - Ax, CAy = Cy - Ay;
      float den = BAx * DCy - BAy * DCx;
      bool dok = fabsf(den) > 1e-12f;
      float dens = dok ? den : 1.0f;
      float t = (CAx * DCy - CAy * DCx) / dens;
      float u = (CAx * BAy - CAy * BAx) / dens;
      int id = e * 4 + f;
      ptsx[id] = Ax + t * BAx;
      ptsy[id] = Ay + t * BAy;
      msk[id] = dok && (t >= 0.0f) && (t <= 1.0f) && (u >= 0.0f) && (u <= 1.0f);
    }
  }
  float xcj = Pj[8], ycj = Pj[9], cj = Pj[10], sj = Pj[11], w2j = Pj[12], h2j = Pj[13];
  float xci = Pi[8], yci = Pi[9], ci = Pi[10], si = Pi[11], w2i = Pi[12], h2i = Pi[13];
#pragma unroll
  for (int k = 0; k < 4; k++) {
    float dx = ax[k] - xcj, dy = ay[k] - ycj;
    float xl = dx * cj + dy * sj;
    float yl = -dx * sj + dy * cj;
    ptsx[16 + k] = ax[k]; ptsy[16 + k] = ay[k];
    msk[16 + k] = (fabsf(xl) <= w2j + 1e-5f) && (fabsf(yl) <= h2j + 1e-5f);
  }
#pragma unroll
  for (int k = 0; k < 4; k++) {
    float dx = bx[k] - xci, dy = by[k] - yci;
    float xl = dx * ci + dy * si;
    float yl = -dx * si + dy * ci;
    ptsx[20 + k] = bx[k]; ptsy[20 + k] = by[k];
    msk[20 + k] = (fabsf(xl) <= w2i + 1e-5f) && (fabsf(yl) <= h2i + 1e-5f);
  }
  int cnt = 0;
  float sx = 0.f, sy = 0.f;
#pragma unroll
  for (int k = 0; k < 24; k++) {
    if (msk[k]) { cnt++; sx += ptsx[k]; sy += ptsy[k]; }
  }
  float fc = (float)(cnt > 1 ? cnt : 1);
  float ctx = sx / fc, cty = sy / fc;
  float ang[32], px[32], py[32];
  int idp[32];
#pragma unroll
  for (int k = 0; k < 24; k++) {
    float rx = ptsx[k] - ctx, ry = ptsy[k] - cty;
    px[k] = rx; py[k] = ry; idp[k] = k;
    ang[k] = msk[k] ? (float)atan2((double)ry, (double)rx) : 1.0e3f;
  }
#pragma unroll
  for (int k = 24; k < 32; k++) { ang[k] = 1.0e30f; px[k] = 0.f; py[k] = 0.f; idp[k] = k; }
#pragma unroll
  for (int k = 2; k <= 32; k <<= 1) {
#pragma unroll
    for (int j = k >> 1; j > 0; j >>= 1) {
#pragma unroll
      for (int x = 0; x < 32; x++) {
        int l = x ^ j;
        if (l > x) {
          bool up = ((x & k) == 0);
          bool gt = (ang[x] > ang[l]) || (ang[x] == ang[l] && idp[x] > idp[l]);
          if (gt == up) {
            float t0 = ang[x]; ang[x] = ang[l]; ang[l] = t0;
            float t1 = px[x]; px[x] = px[l]; px[l] = t1;
            float t2 = py[x]; py[x] = py[l]; py[l] = t2;
            int t3 = idp[x]; idp[x] = idp[l]; idp[l] = t3;
          }
        }
      }
    }
  }
  float term[24];
#pragma unroll
  for (int x = 0; x < 24; x++) {
    int nx = (x + 1 < cnt) ? x + 1 : 0;
    float cr = px[x] * py[nx] - py[x] * px[nx];
    term[x] = (x < cnt) ? cr : 0.0f;
  }
  float r[8];
#pragma unroll
  for (int j = 0; j < 8; j++) r[j] = (term[j] + term[j + 8]) + term[j + 16];
  float ssum = ((r[0] + r[1]) + (r[2] + r[3])) + ((r[4] + r[5]) + (r[6] + r[7]));
  float area = 0.5f * fabsf(ssum);
  float inter = (cnt >= 3) ? area : 0.0f;
  float iou = inter / ((Pi[14] + Pj[14] - inter) + 1e-9f);
  return (iou > 0.3f) ? (1.0f - iou) : 1.0f;
}

// Heavy geometry on candidates (grid-stride); emit sparse edge iff w != 1.
__global__ __launch_bounds__(64, 2) void weight_kernel(const float* __restrict__ prep,
                                                       const uint* __restrict__ cand,
                                                       const uint* __restrict__ ccnt,
                                                       ull* __restrict__ etmp,
                                                       uint* __restrict__ ecnt,
                                                       uint* __restrict__ rowcnt,
                                                       uint* __restrict__ mark) {
  uint n = *ccnt;
  if (n > CCAP) n = CCAP;
  for (uint idx = blockIdx.x * 64u + threadIdx.x; idx < n; idx += gridDim.x * 64u) {
    uint pk = cand[idx];
    uint i = pk >> 11, j = pk & 2047u;
    float w = pair_weight(prep + i * PSTRIDE, prep + j * PSTRIDE);
    if (w != 1.0f) {
      uint pos = atomicAdd(ecnt, 1u);
      if (pos < ECAP) {
        etmp[pos] = (((ull)__float_as_uint(w)) << 32) | (ull)pk;
        atomicAdd(rowcnt + i, 1u);
        mark[i] = 1u;
        mark[j] = 1u;
      }
    }
  }
}

// CSR finalize + edge scatter fused (one workgroup, LDS cursors).
__global__ __launch_bounds__(1024) void csr_fin(uint* __restrict__ rinfo,
                                                const uint* __restrict__ mark,
                                                ushort* __restrict__ mlist,
                                                uint* __restrict__ gcm,
                                                uint* __restrict__ mcount,
                                                const ull* __restrict__ etmp,
                                                const uint* __restrict__ ecnt,
                                                ull* __restrict__ ecsr) {
  __shared__ uint pre[N];
  __shared__ uint curL[N];
  __shared__ uint msh;
  int tid = threadIdx.x;
  uint c0 = rinfo[tid], c1 = rinfo[tid + 1024];
  pre[tid] = c0; pre[tid + 1024] = c1;
  if (tid == 0) msh = 0;
  __syncthreads();
  for (int d = 1; d < N; d <<= 1) {
    uint a0 = pre[tid] + ((tid >= d) ? pre[tid - d] : 0);
    uint a1 = pre[tid + 1024] + ((tid + 1024 >= d) ? pre[tid + 1024 - d] : 0);
    __syncthreads();
    pre[tid] = a0; pre[tid + 1024] = a1;
    __syncthreads();
  }
  uint p0 = pre[tid] - c0, p1 = pre[tid + 1024] - c1;
  rinfo[tid] = p0 | (c0 << 20);
  rinfo[tid + 1024] = p1 | (c1 << 20);
  curL[tid] = p0;
  curL[tid + 1024] = p1;
  if (mark[tid]) { uint m = atomicAdd(&msh, 1u); mlist[m] = (ushort)tid; gcm[tid] = m; }
  if (mark[tid + 1024]) { uint m = atomicAdd(&msh, 1u); mlist[m] = (ushort)(tid + 1024); gcm[tid + 1024] = m; }
  __syncthreads();
  if (tid == 0) *mcount = msh;
  uint E = *ecnt;
  if (E > ECAP) E = ECAP;
  for (uint e = (uint)tid; e < E; e += 1024u) {
    ull ed = etmp[e];
    uint lo = (uint)ed;
    uint i = (lo >> 11) & 2047u, j = lo & 2047u;
    uint pos = atomicAdd(&curL[i], 1u);
    ecsr[pos] = (ed & 0xFFFFFFFF00000000ull) | (ull)gcm[j];
  }
}

// Sequential soft-NMS over members, ONE wave. Per-lane register TOP-4 with
// static lower bound Bs (= 4th-best at rebuild). Decays only shrink values,
// so untracked <= Bs forever. Validation = exact refresh from LDS (no drops),
// 5-compare CE re-sort; rebuild ONLY if k0==0 (depleted) or k0 < Bs
// (invariant lost). Rebuild uses 8-wide batched LDS loads.
__global__ __launch_bounds__(64) void scan_sub(const float* __restrict__ scores,
                                               const ushort* __restrict__ mlist,
                                               const uint* __restrict__ mcount,
                                               const uint* __restrict__ rinfo_g,
                                               const ull* __restrict__ ecsr,
                                               const uint* __restrict__ ecnt,
                                               const uint* __restrict__ mark,
                                               ull* __restrict__ kout) {
#pragma clang fp contract(off)
  __shared__ ull mkey[N];
  __shared__ uint rinfo[N];
  __shared__ ull eld[ELCAP];
  const int lane = threadIdx.x;
#pragma unroll
  for (int k = 0; k < 8; k++) {
    int i4 = lane + 64 * k;
    ((uint4*)rinfo)[i4] = ((const uint4*)rinfo_g)[i4];
  }
#pragma unroll
  for (int k = 0; k < 32; k++) mkey[lane + 64 * k] = 0ull;
#pragma unroll
  for (int k = 0; k < 32; k++) {
    int col = lane + 64 * k;
    if (!mark[col]) {
      uint b = __float_as_uint(scores[col]);
      kout[col] = (((ull)b) << 32) | (ull)(uint)(2048 - col);
    }
  }
  uint E = *ecnt;
  if (E > ECAP) E = ECAP;
  bool use_lds = (E <= ELCAP);
  if (use_lds) {
    uint n4 = (E + 1) >> 1;
    for (uint q = (uint)lane; q < n4; q += 64u)
      ((uint4*)eld)[q] = ((const uint4*)ecsr)[q];
  }
  int M = (int)*mcount;
  int nsl = (M + 63) >> 6;
  for (int g = 0; g < nsl; g++) {
    int m = lane + 64 * g;
    if (m < M) {
      int col = (int)mlist[m];
      uint b = __float_as_uint(scores[col]);
      mkey[m] = (((ull)b) << 32) | (ull)(uint)(2048 - col);
    }
  }
  asm volatile("s_waitcnt lgkmcnt(0) vmcnt(0)" ::: "memory");
  ull k0 = 0, k1 = 0, k2 = 0, k3 = 0, Bs = 0;
  int m0 = -1, m1 = -1, m2 = -1, m3 = -1;
  bool done = false;
  // top-4 insert (predicated, no branches)
#define INS(kk, mm)                                                            \
  {                                                                            \
    ull _k = (kk); int _m = (mm);                                              \
    bool g0 = _k > k0, g1 = _k > k1, g2 = _k > k2, g3 = _k > k3;               \
    k3 = g2 ? k2 : (g3 ? _k : k3); m3 = g2 ? m2 : (g3 ? _m : m3);              \
    k2 = g1 ? k1 : (g2 ? _k : k2); m2 = g1 ? m1 : (g2 ? _m : m2);              \
    k1 = g0 ? k0 : (g1 ? _k : k1); m1 = g0 ? m0 : (g1 ? _m : m1);              \
    k0 = g0 ? _k : k0;             m0 = g0 ? _m : m0;                          \
  }
  auto rebuild = [&]() {
    k0 = k1 = k2 = k3 = 0;
    m0 = m1 = m2 = m3 = -1;
    int g = 0;
    for (; g + 8 <= nsl; g += 8) {
      ull t0 = mkey[lane + 64 * (g + 0)], t1 = mkey[lane + 64 * (g + 1)];
      ull t2 = mkey[lane + 64 * (g + 2)], t3 = mkey[lane + 64 * (g + 3)];
      ull t4 = mkey[lane + 64 * (g + 4)], t5 = mkey[lane + 64 * (g + 5)];
      ull t6 = mkey[lane + 64 * (g + 6)], t7 = mkey[lane + 64 * (g + 7)];
      INS(t0, lane + 64 * (g + 0)); INS(t1, lane + 64 * (g + 1));
      INS(t2, lane + 64 * (g + 2)); INS(t3, lane + 64 * (g + 3));
      INS(t4, lane + 64 * (g + 4)); INS(t5, lane + 64 * (g + 5));
      INS(t6, lane + 64 * (g + 6)); INS(t7, lane + 64 * (g + 7));
    }
    for (; g < nsl; g++) {
      int m = lane + 64 * g;
      if (m < M) { ull k = mkey[m]; INS(k, m); }
    }
    Bs = k3;           // untracked <= Bs forever (decays only shrink)
    done = (k0 == 0);  // lane fully consumed
  };
  rebuild();
  for (int t = 0; t < M; ++t) {
    uint hi = (uint)(k0 >> 32);
    uint ghi = wave_umax_bcast(hi);
    if (!((double)__uint_as_float(ghi) > 0.001)) break;
    uint lo = (uint)k0;
    uint cnd = (hi == ghi) ? lo : 0u;
    uint glo = wave_umax_bcast(cnd);
    int bj = 2048 - (int)glo;
    if (hi == ghi && lo == glo && k0 != 0ull) {  // unique owner pops
      mkey[m0] = 0ull;
      kout[bj] = (((ull)ghi) << 32) | (ull)glo;
      k0 = k1; m0 = m1; k1 = k2; m1 = m2; k2 = k3; m2 = m3; k3 = 0; m3 = -1;
    }
    uint info = rinfo[bj];
    uint ptr = info & 0xFFFFFu;
    uint deg = info >> 20;
    if (use_lds) {
      for (uint e = (uint)lane; e < deg; e += 64u) {
        ull ed = eld[ptr + e];
        uint mt = (uint)ed & 2047u;
        float w = __uint_as_float((uint)(ed >> 32));
        ull ok = mkey[mt];
        float nv = __uint_as_float((uint)(ok >> 32)) * w;
        mkey[mt] = (((ull)__float_as_uint(nv)) << 32) | (ok & 0xFFFFFFFFull);
      }
    } else {
      for (uint e = (uint)lane; e < deg; e += 64u) {
        ull ed = ecsr[ptr + e];
        uint mt = (uint)ed & 2047u;
        float w = __uint_as_float((uint)(ed >> 32));
        ull ok = mkey[mt];
        float nv = __uint_as_float((uint)(ok >> 32)) * w;
        mkey[mt] = (((ull)__float_as_uint(nv)) << 32) | (ok & 0xFFFFFFFFull);
      }
    }
    asm volatile("s_waitcnt lgkmcnt(0)" ::: "memory");
    // EXACT refresh of tracked entries from LDS (no drops), then re-sort.
    if (m0 >= 0) k0 = mkey[m0];
    if (m1 >= 0) k1 = mkey[m1];
    if (m2 >= 0) k2 = mkey[m2];
    if (m3 >= 0) k3 = mkey[m3];
    {
      ull tk; int tm;
#define CE(x, y, mx, my) if (x < y) { tk = x; x = y; y = tk; tm = mx; mx = my; my = tm; }
      CE(k0, k1, m0, m1) CE(k2, k3, m2, m3) CE(k0, k2, m0, m2) CE(k1, k3, m1, m3) CE(k1, k2, m1, m2)
#undef CE
    }
    if (!done && (k0 == 0ull || k0 < Bs)) rebuild();
  }
  asm volatile("s_waitcnt lgkmcnt(0)" ::: "memory");
  for (int g = 0; g < nsl; g++) {
    int m = lane + 64 * g;
    if (m < M) {
      ull key = mkey[m];
      if (key != 0ull) {
        int col = 2048 - (int)(uint)key;
        kout[col] = key;
      }
    }
  }
#undef INS
}

// Sort 2048 keys descending and emit (order, keep, rec). Proven r11-r14.
__global__ __launch_bounds__(1024) void sort_out(const ull* __restrict__ kout,
                                                 float* __restrict__ out) {
  __shared__ ull keys[N];
  int tid = threadIdx.x;
  keys[tid] = kout[tid];
  keys[tid + 1024] = kout[tid + 1024];
  __syncthreads();
  for (int k = 2; k <= N; k <<= 1) {
    for (int jj = k >> 1; jj > 0; jj >>= 1) {
      int i1 = ((tid & ~(jj - 1)) << 1) | (tid & (jj - 1));
      int i2 = i1 | jj;
      ull a = keys[i1], b = keys[i2];
      bool up = ((i1 & k) == 0);
      if (up ? (a < b) : (a > b)) { keys[i1] = b; keys[i2] = a; }
      __syncthreads();
    }
  }
#pragma unroll
  for (int h = 0; h < 2; h++) {
    int r = tid + 1024 * h;
    ull key = keys[r];
    int col = 2048 - (int)(uint)key;
    float v = __uint_as_float((uint)(key >> 32));
    out[r] = (float)col;
    out[N + r] = ((double)v > 0.001) ? 1.0f : 0.0f;
    out[2 * N + r] = v;
  }
}

// Tiny-ws fallback: on-the-fly dense scan (proven round 8 structure).
__global__ __launch_bounds__(1024) void scan_fly(const float* __restrict__ prep,
                                                 const float* __restrict__ scores,
                                                 float* __restrict__ out) {
  __shared__ float sc[N];
  __shared__ unsigned char sel[N];
  __shared__ float rv[16];
  __shared__ int ri[16];
  int tid = threadIdx.x;
  sc[tid] = scores[tid];
  sc[tid + 1024] = scores[tid + 1024];
  sel[tid] = 0;
  sel[tid + 1024] = 0;
  __syncthreads();
  const float NINF = -__builtin_inff();
  for (int t = 0; t < N; ++t) {
    float v0 = sel[tid] ? NINF : sc[tid];
    float v1 = sel[tid + 1024] ? NINF : sc[tid + 1024];
    float bv; int bi;
    if (v0 >= v1) { bv = v0; bi = tid; } else { bv = v1; bi = tid + 1024; }
#pragma unroll
    for (int off = 32; off > 0; off >>= 1) {
      float ov = __shfl_down(bv, off);
      int oi = __shfl_down(bi, off);
      if (ov > bv || (ov == bv && oi < bi)) { bv = ov; bi = oi; }
    }
    if ((tid & 63) == 0) { rv[tid >> 6] = bv; ri[tid >> 6] = bi; }
    __syncthreads();
    float mv = rv[0]; int mi = ri[0];
#pragma unroll
    for (int k = 1; k < 16; k++) {
      float ov = rv[k]; int oi = ri[k];
      if (ov > mv || (ov == mv && oi < mi)) { mv = ov; mi = oi; }
    }
    if (tid == 0) {
      out[t] = (float)mi;
      out[N + t] = (mv > 0.001f) ? 1.0f : 0.0f;
      out[2 * N + t] = mv;
    }
    if (tid == (mi & 1023)) sel[mi] = 1;
    if (mv > 0.001f) {
      const float* Pm = prep + mi * PSTRIDE;
#pragma unroll
      for (int half = 0; half < 2; half++) {
        int j = tid + half * 1024;
        if (!sel[j]) {
          const float* Pj = prep + j * PSTRIDE;
          float dx = Pm[8] - Pj[8], dy = Pm[9] - Pj[9];
          float rr = Pm[15] + Pj[15] + 1.0f;
          float w = 1.0f;
          if (dx * dx + dy * dy <= rr * rr) w = pair_weight(Pm, Pj);
          sc[j] *= w;
        }
      }
    }
    __syncthreads();
  }
}

extern "C" void kernel_launch(void* const* d_in, const int* in_sizes, int n_in,
                              void* d_out, int out_size, void* d_ws, size_t ws_size,
                              hipStream_t stream) {
  const float* boxes = (const float*)d_in[0];
  const float* scores = (const float*)d_in[1];
  if (n_in >= 2 && in_sizes[0] == N && in_sizes[1] == 5 * N) {
    boxes = (const float*)d_in[1];
    scores = (const float*)d_in[0];
  }
  float* out = (float*)d_out;
  char* ws = (char*)d_ws;
  uint* ccnt = (uint*)(ws + CTR_OFF);
  uint* ecnt = (uint*)(ws + CTR_OFF + 64);
  uint* mcount = (uint*)(ws + CTR_OFF + 128);
  float* prep = (float*)(ws + PREP_OFF);

  if (ws_size >= NEED) {
    uint* cand = (uint*)(ws + CAND_OFF);
    ull* etmp = (ull*)(ws + ETMP_OFF);
    ull* ecsr = (ull*)(ws + ECSR_OFF);
    uint* rinfo = (uint*)(ws + RINF_OFF);
    uint* mark = (uint*)(ws + MARK_OFF);
    uint* gcm = (uint*)(ws + GCM_OFF);
    ushort* mlist = (ushort*)(ws + MLIST_OFF);
    ull* kout = (ull*)(ws + KOUT_OFF);
    prep_kernel<<<8, 256, 0, stream>>>(boxes, prep, (uint*)ws, rinfo, mark);
    cand_kernel<<<4096, 256, 0, stream>>>(prep, cand, ccnt);
    weight_kernel<<<1024, 64, 0, stream>>>(prep, cand, ccnt, etmp, ecnt, rinfo, mark);
    csr_fin<<<1, 1024, 0, stream>>>(rinfo, mark, mlist, gcm, mcount, etmp, ecnt, ecsr);
    scan_sub<<<1, 64, 0, stream>>>(scores, mlist, mcount, rinfo, ecsr, ecnt, mark, kout);
    sort_out<<<1, 1024, 0, stream>>>(kout, out);
  } else {
    prep_kernel<<<8, 256, 0, stream>>>(boxes, prep, (uint*)ws,
                                       (uint*)(ws + 256 + 196608),
                                       (uint*)(ws + 256 + 196608 + 8192));
    scan_fly<<<1, 1024, 0, stream>>>(prep, scores, out);
  }
}